// Round 15
// baseline (54.902 us; speedup 1.0000x reference)
//
#include <hip/hip_runtime.h>

typedef __bf16 bhalf;
typedef bhalf bhalf8 __attribute__((ext_vector_type(8)));
typedef float f32x4 __attribute__((ext_vector_type(4)));
typedef unsigned short u16;
typedef u16 u16x8 __attribute__((ext_vector_type(8)));

__device__ __forceinline__ u16 f2bf(float f) {
  union { float f; unsigned u; } v; v.f = f;
  unsigned r = v.u + 0x7FFFu + ((v.u >> 16) & 1u);
  return (u16)(r >> 16);
}

// Involutions flipping byte bits 4-6:
// swz  : key bits 7-9 (64B-row staging tiles; proven r5-r14, 0 conflicts)
// swzM : key (row ^ row>>3)&7 for the 1024B-row m1 tile (r14)
__device__ __forceinline__ int swz(int L)  { return L ^ (((L >> 7) & 7) << 4); }
__device__ __forceinline__ int swzM(int L) { return L ^ ((((L >> 10) ^ (L >> 13)) & 7) << 4); }

#define GLL16(gp, lp) __builtin_amdgcn_global_load_lds( \
    (const __attribute__((address_space(1))) unsigned int*)(gp), \
    (__attribute__((address_space(3))) unsigned int*)(lp), 16, 0, 0)

#define SB() __builtin_amdgcn_sched_barrier(0)

// W0: [512][784] f32 -> bf16 [512][800] zero-pad (25 K-tiles of 32); W1: [256][512]; W2 pad.
#define KP0 800
#define W0E (512 * KP0)
#define W1E (256 * 512)
#define W2E (16 * 256)

__global__ __launch_bounds__(256) void cvt_weights(
    const float* __restrict__ W0, const float* __restrict__ W1,
    const float* __restrict__ W2,
    u16* __restrict__ W0b, u16* __restrict__ W1b, u16* __restrict__ W2b)
{
  int i = blockIdx.x * 256 + threadIdx.x;
  if (i < W0E) {
    int r = i / KP0, k = i - r * KP0;
    W0b[i] = (k < 784) ? f2bf(W0[r * 784 + k]) : (u16)0;
    return;
  }
  i -= W0E;
  if (i < W1E) { W1b[i] = f2bf(W1[i]); return; }
  i -= W1E;
  if (i < W2E) {
    int r = i >> 8, c = i & 255;
    W2b[i] = (r < 10) ? f2bf(W2[r * 256 + c]) : (u16)0;
  }
}

// FUSED 3 layers (r14) with DEEPENED layer-1 staging: BK=32, 25 K-tiles, B in a
// 3x32KB rotation staged 2 K-TILES ahead (vmcnt slack 2x the VMEM service time),
// x 2 tiles ahead in ping-pong reg sets. 2 phases/K-tile, vmcnt(6) once per tile.
// LDS: A dbuf 16KB @0 | B rot 96KB @16384 | W1 dbuf 32KB @131072; m1 reuses 0..128K.
__global__ __launch_bounds__(512) void fused3(
    const float* __restrict__ x, const u16* __restrict__ Wb,
    const u16* __restrict__ W1b, const u16* __restrict__ W2b,
    float* __restrict__ out)
{
  extern __shared__ u16 ldsu[];      // 160 KB dynamic
  char* lds = (char*)ldsu;
  const int t = threadIdx.x, w = t >> 6, lane = t & 63;
  const size_t rbase = (size_t)blockIdx.x * 128;
  const int wr = w >> 2, wc = w & 3, fr = lane & 15, fg = lane >> 4;

  // ================= layer 1: 128x512, BK=32, 8 waves (2Mx4N) =================
  int aO[4], bO[8];
#pragma unroll
  for (int m = 0; m < 4; ++m) aO[m] = swz((wr * 64 + m * 16 + fr) * 64 + fg * 16);
#pragma unroll
  for (int n = 0; n < 8; ++n) bO[n] = swz((wc * 128 + n * 16 + fr) * 64 + fg * 16);

  // B staging: 32KB tile = 4 x 1KB gll per wave; source pre-swizzled
  const u16* bSrcP[4];
#pragma unroll
  for (int i = 0; i < 4; ++i) {
    int P = (w * 4 + i) * 1024 + lane * 16;
    int U = swz(P);
    bSrcP[i] = Wb + (size_t)(U >> 6) * KP0 + ((U & 63) >> 1);
  }
  // A staging: 1 chunk/thread (16B bf16 dest = 8 f32 src)
  const float* xRow; int aKe;
  {
    int P = t * 16;
    int U = swz(P);
    xRow = x + (rbase + (U >> 6)) * (size_t)784;
    aKe = (U & 63) >> 1;
  }

  f32x4 acc[4][8];
#pragma unroll
  for (int m = 0; m < 4; ++m)
#pragma unroll
    for (int n = 0; n < 8; ++n) acc[m][n] = (f32x4){0.f, 0.f, 0.f, 0.f};

  bhalf8 afA[4], bf[4];
  f32x4 xrE[2], xrO[2];   // two static ping-pong x sets (rule #20)

  auto loadX = [&](int s, f32x4 (&xr)[2]) {
    int k = s * 32 + aKe;
    const float* p = xRow + ((k < 784) ? k : 0);   // clamp; W0b zero-padded there
    xr[0] = *(const f32x4*)p; xr[1] = *(const f32x4*)(p + 4);
  };
  auto cvtW = [&](int aB, f32x4 (&xr)[2]) {
    u16x8 v;
#pragma unroll
    for (int j = 0; j < 4; ++j) { v[j] = f2bf(xr[0][j]); v[4 + j] = f2bf(xr[1][j]); }
    *(u16x8*)(lds + aB + t * 16) = v;
  };
  auto rdA = [&](int aB) {
#pragma unroll
    for (int m = 0; m < 4; ++m) afA[m] = *(const bhalf8*)(lds + aB + aO[m]);
  };
  auto rdBq = [&](const char* bb, int hi) {
#pragma unroll
    for (int j = 0; j < 4; ++j) bf[j] = *(const bhalf8*)(bb + bO[hi * 4 + j]);
  };
  auto mfmaLo = [&]() {
    __builtin_amdgcn_s_setprio(1);
#pragma unroll
    for (int m = 0; m < 4; ++m)
#pragma unroll
      for (int n = 0; n < 4; ++n)
        acc[m][n] = __builtin_amdgcn_mfma_f32_16x16x32_bf16(afA[m], bf[n], acc[m][n], 0, 0, 0);
    __builtin_amdgcn_s_setprio(0);
  };
  auto mfmaHi = [&]() {
    __builtin_amdgcn_s_setprio(1);
#pragma unroll
    for (int m = 0; m < 4; ++m)
#pragma unroll
      for (int n = 0; n < 4; ++n)
        acc[m][4 + n] = __builtin_amdgcn_mfma_f32_16x16x32_bf16(afA[m], bf[n], acc[m][4 + n], 0, 0, 0);
    __builtin_amdgcn_s_setprio(0);
  };

  // tile body: 2 phases, staged 2 K-tiles ahead
  auto tile = [&](int tt, f32x4 (&xLd)[2], f32x4 (&xCv)[2],
                  bool doStage, bool doX, bool doCvt, int vmEnd) {
    const int aB = (tt & 1) * 8192;
    const char* bbCur = lds + 16384 + (tt % 3) * 32768;
    char* bbNxt = lds + 16384 + ((tt + 2) % 3) * 32768;
    // ---- Ph1: A + B-lo reads; issue half of B(tt+2) + x(tt+2) ----
    rdA(aB); rdBq(bbCur, 0);
    if (doStage) {
      GLL16(bSrcP[0] + (tt + 2) * 32, bbNxt + (w * 4 + 0) * 1024);
      GLL16(bSrcP[1] + (tt + 2) * 32, bbNxt + (w * 4 + 1) * 1024);
    }
    if (doX) loadX(tt + 2, xLd);
    __builtin_amdgcn_s_barrier();
    asm volatile("s_waitcnt lgkmcnt(0)" ::: "memory"); SB();
    mfmaLo();
    __builtin_amdgcn_s_barrier();
    // ---- Ph2: B-hi reads; cvt A(tt+1); second half of B(tt+2) ----
    rdBq(bbCur, 1);
    if (doCvt) cvtW(aB ^ 8192, xCv);     // auto-waits x(tt+1) via reg dep
    if (doStage) {
      GLL16(bSrcP[2] + (tt + 2) * 32, bbNxt + (w * 4 + 2) * 1024);
      GLL16(bSrcP[3] + (tt + 2) * 32, bbNxt + (w * 4 + 3) * 1024);
    }
    __builtin_amdgcn_s_barrier();
    asm volatile("s_waitcnt lgkmcnt(0)" ::: "memory"); SB();
    mfmaHi();
    if (vmEnd == 6)      { asm volatile("s_waitcnt vmcnt(6)" ::: "memory"); }
    else if (vmEnd == 0) { asm volatile("s_waitcnt vmcnt(0)" ::: "memory"); }
    __builtin_amdgcn_s_barrier();
  };

  // ---- prologue: B(0), B(1) in flight; x(0)->xrE consumed into A0; x(1)->xrO ----
#pragma unroll
  for (int i = 0; i < 4; ++i) GLL16(bSrcP[i], lds + 16384 + (w * 4 + i) * 1024);
  loadX(0, xrE);
#pragma unroll
  for (int i = 0; i < 4; ++i) GLL16(bSrcP[i] + 32, lds + 16384 + 32768 + (w * 4 + i) * 1024);
  loadX(1, xrO);
  cvtW(0, xrE);    // implied vmcnt drains B(0)+x(0); B(1)+x(1) stay in flight
  asm volatile("s_waitcnt lgkmcnt(0)" ::: "memory");
  __builtin_amdgcn_s_barrier();

  // ---- tiles 0..21 (full pipeline), 22 (last stage/x), 23, 24 (drain) ----
  for (int i = 0; i < 11; ++i) {
    tile(2 * i,     xrE, xrO, true, true, true, 6);
    tile(2 * i + 1, xrO, xrE, true, true, true, 6);
  }
  tile(22, xrE, xrO, true,  true,  true,  6);   // stages B(24), loads x(24)
  tile(23, xrO, xrE, false, false, true,  0);   // cvt A(24); drain all VMEM
  tile(24, xrE, xrO, false, false, false, -1);
  __builtin_amdgcn_s_barrier();   // all waves done reading staging LDS

  // ====== layer-2 W1 staging sources (pre-swizzled [256][32] 64B-row tiles) ======
  const u16* w1Src[2];
#pragma unroll
  for (int i = 0; i < 2; ++i) {
    int P = (w * 2 + i) * 1024 + lane * 16;
    int U = swz(P);
    w1Src[i] = W1b + (size_t)(U >> 6) * 512 + ((U & 63) >> 1);
  }
  // issue W1 tile-0 glls now: they fly under the m1 scatter
#pragma unroll
  for (int i = 0; i < 2; ++i) GLL16(w1Src[i], lds + 131072 + (w * 2 + i) * 1024);

  // ====== scatter relu(m1) -> LDS [128][512] bf16 (swzM); acc dies here ======
#pragma unroll
  for (int m = 0; m < 4; ++m)
#pragma unroll
    for (int n = 0; n < 8; ++n)
#pragma unroll
      for (int q = 0; q < 4; ++q) {
        int row = wr * 64 + m * 16 + fg * 4 + q;
        int col = wc * 128 + n * 16 + fr;
        float vv = acc[m][n][q];
        vv = vv > 0.f ? vv : 0.f;
        *(u16*)(lds + swzM(row * 1024 + col * 2)) = f2bf(vv);
      }
  __syncthreads();

  // ====== layer 2: m2[128][256] = relu(m1 @ W1^T), K=512, BK=32, 16 dbuf steps ======
  int a2O[4], b2O[4];
#pragma unroll
  for (int m = 0; m < 4; ++m) a2O[m] = (wr * 64 + m * 16 + fr) * 1024 + fg * 16;
#pragma unroll
  for (int n = 0; n < 4; ++n) b2O[n] = (wc * 64 + n * 16 + fr) * 64 + fg * 16;

  f32x4 acc2[4][4];
#pragma unroll
  for (int m = 0; m < 4; ++m)
#pragma unroll
    for (int n = 0; n < 4; ++n) acc2[m][n] = (f32x4){0.f, 0.f, 0.f, 0.f};

  for (int kt = 0; kt < 16; ++kt) {
    const char* wbuf = lds + 131072 + (kt & 1) * 16384;
    asm volatile("s_waitcnt vmcnt(0)" ::: "memory");
    __syncthreads();
    if (kt < 15) {
#pragma unroll
      for (int i = 0; i < 2; ++i)
        GLL16(w1Src[i] + (kt + 1) * 32,
              lds + 131072 + ((kt + 1) & 1) * 16384 + (w * 2 + i) * 1024);
    }
    bhalf8 a2[4], b2[4];
#pragma unroll
    for (int m = 0; m < 4; ++m)
      a2[m] = *(const bhalf8*)(lds + swzM(a2O[m] + kt * 64));
#pragma unroll
    for (int n = 0; n < 4; ++n)
      b2[n] = *(const bhalf8*)(wbuf + swz(b2O[n]));
    __builtin_amdgcn_s_setprio(1);
#pragma unroll
    for (int m = 0; m < 4; ++m)
#pragma unroll
      for (int n = 0; n < 4; ++n)
        acc2[m][n] = __builtin_amdgcn_mfma_f32_16x16x32_bf16(a2[m], b2[n], acc2[m][n], 0, 0, 0);
    __builtin_amdgcn_s_setprio(0);
  }
  __syncthreads();   // all m1 / W1-buf reads done; LDS reusable

  // ====== m2 -> LDS [128][264] @0; W2 [16][264] @67584; layer 3 -> out ======
  u16* m2s = (u16*)lds;
  u16* W2s = (u16*)(lds + 67584);
  {
    int r = t >> 5, kc = (t & 31) * 8;
    *(int4*)&W2s[r * 264 + kc] = *(const int4*)(W2b + r * 256 + kc);
  }
#pragma unroll
  for (int m = 0; m < 4; ++m)
#pragma unroll
    for (int n = 0; n < 4; ++n)
#pragma unroll
      for (int q = 0; q < 4; ++q) {
        int row = wr * 64 + m * 16 + fg * 4 + q;
        int col = wc * 64 + n * 16 + fr;
        float vv = acc2[m][n][q];
        vv = vv > 0.f ? vv : 0.f;
        m2s[row * 264 + col] = f2bf(vv);
      }
  __syncthreads();

  // layer 3: 8 waves x 16 rows, K=256
  {
    f32x4 acc3 = (f32x4){0.f, 0.f, 0.f, 0.f};
    const int arow = w * 16 + fr;
#pragma unroll
    for (int ks = 0; ks < 8; ++ks) {
      bhalf8 a = *(const bhalf8*)&m2s[arow * 264 + ks * 32 + fg * 8];
      bhalf8 b = *(const bhalf8*)&W2s[fr * 264 + ks * 32 + fg * 8];
      acc3 = __builtin_amdgcn_mfma_f32_16x16x32_bf16(a, b, acc3, 0, 0, 0);
    }
    if (fr < 10) {
#pragma unroll
      for (int q = 0; q < 4; ++q) {
        size_t row = rbase + w * 16 + fg * 4 + q;
        float vv = acc3[q];
        out[row * 10 + fr] = vv > 0.f ? vv : 0.f;
      }
    }
  }
}

extern "C" void kernel_launch(void* const* d_in, const int* in_sizes, int n_in,
                              void* d_out, int out_size, void* d_ws, size_t ws_size,
                              hipStream_t stream) {
  const float* x  = (const float*)d_in[0];
  const float* W0 = (const float*)d_in[1];
  const float* W1 = (const float*)d_in[2];
  const float* W2 = (const float*)d_in[3];
  float* out = (float*)d_out;

  char* ws = (char*)d_ws;
  u16* W0b = (u16*)(ws);                    // 512x800 = 819200 B
  u16* W1b = (u16*)(ws + 819200);           // 256x512 = 262144 B
  u16* W2b = (u16*)(ws + 1081344);          // 16x256  = 8192 B

  hipFuncSetAttribute((const void*)fused3,
                      hipFuncAttributeMaxDynamicSharedMemorySize, 163840);

  cvt_weights<<<dim3((W0E + W1E + W2E + 255) / 256), dim3(256), 0, stream>>>(
      W0, W1, W2, W0b, W1b, W2b);

  // all three layers fused; B staged 2 K-tiles ahead
  fused3<<<dim3(256), dim3(512), 163840, stream>>>(x, W0b, W1b, W2b, out);
}

// Round 16
// 53.965 us; speedup vs baseline: 1.0174x; 1.0174x over previous
//
#include <hip/hip_runtime.h>

typedef __bf16 bhalf;
typedef bhalf bhalf8 __attribute__((ext_vector_type(8)));
typedef float f32x4 __attribute__((ext_vector_type(4)));
typedef unsigned short u16;
typedef u16 u16x8 __attribute__((ext_vector_type(8)));

__device__ __forceinline__ u16 f2bf(float f) {
  union { float f; unsigned u; } v; v.f = f;
  unsigned r = v.u + 0x7FFFu + ((v.u >> 16) & 1u);
  return (u16)(r >> 16);
}

// Involutions flipping byte bits 4-6:
// swz  : key bits 7-9   (64B/128B-row staging tiles; 0 conflicts, proven r5-r14)
// swzM : key (row ^ row>>3)&7 for 1024B-row m1 tile — conflict-light on scatter
//        writes (keys {0,4,1,5} across fg) and free 2-way on layer-2 row reads.
__device__ __forceinline__ int swz(int L)  { return L ^ (((L >> 7) & 7) << 4); }
__device__ __forceinline__ int swzM(int L) { return L ^ ((((L >> 10) ^ (L >> 13)) & 7) << 4); }

#define GLL16(gp, lp) __builtin_amdgcn_global_load_lds( \
    (const __attribute__((address_space(1))) unsigned int*)(gp), \
    (__attribute__((address_space(3))) unsigned int*)(lp), 16, 0, 0)

#define SB() __builtin_amdgcn_sched_barrier(0)

// W0: [512][784] f32 -> bf16 [512][832] zero-pad (13 K-tiles of 64); W1: [256][512]; W2 pad 16x256.
#define KP0 832
#define W0E (512 * KP0)
#define W1E (256 * 512)
#define W2E (16 * 256)

__global__ __launch_bounds__(256) void cvt_weights(
    const float* __restrict__ W0, const float* __restrict__ W1,
    const float* __restrict__ W2,
    u16* __restrict__ W0b, u16* __restrict__ W1b, u16* __restrict__ W2b)
{
  int i = blockIdx.x * 256 + threadIdx.x;
  if (i < W0E) {
    int r = i / KP0, k = i - r * KP0;
    W0b[i] = (k < 784) ? f2bf(W0[r * 784 + k]) : (u16)0;
    return;
  }
  i -= W0E;
  if (i < W1E) { W1b[i] = f2bf(W1[i]); return; }
  i -= W1E;
  if (i < W2E) {
    int r = i >> 8, c = i & 255;
    W2b[i] = (r < 10) ? f2bf(W2[r * 256 + c]) : (u16)0;
  }
}

// FUSED 3 layers, spill-free (round-14 configuration — measured best, 53.8 us).
// Block = 128 rows, 8 waves. Layer-1: 8-phase 128x512 (x read once), m1 stays in
// acc. Immediate full scatter relu(m1)->LDS[128][512] (swzM; acc dies -> no spill).
// Layer-2: K=512 BK=32 dbuf W1 (gll). m2/W2 reuse dead m1 LDS; layer-3 -> out.
// LDS = 160 KB (1 block/CU).
__global__ __launch_bounds__(512) void fused3(
    const float* __restrict__ x, const u16* __restrict__ Wb,
    const u16* __restrict__ W1b, const u16* __restrict__ W2b,
    float* __restrict__ out)
{
  extern __shared__ u16 ldsu[];      // 160 KB dynamic
  char* lds = (char*)ldsu;
  const int t = threadIdx.x, w = t >> 6, lane = t & 63;
  const size_t rbase = (size_t)blockIdx.x * 128;
  const int wr = w >> 2, wc = w & 3, fr = lane & 15, fg = lane >> 4;

  // ================= layer 1 (8-phase, r12 structure) =================
  int aO[4];
#pragma unroll
  for (int m = 0; m < 4; ++m) aO[m] = swz((wr * 64 + m * 16 + fr) * 128 + fg * 16);
  int bO[4];
#pragma unroll
  for (int j = 0; j < 4; ++j) bO[j] = swz((wc * 128 + j * 16 + fr) * 64 + fg * 16);

  const u16* bSrcP[4];
#pragma unroll
  for (int i = 0; i < 4; ++i) {
    int P = (w * 4 + i) * 1024 + lane * 16;
    int U = swz(P);
    bSrcP[i] = Wb + (size_t)(U >> 6) * KP0 + ((U & 63) >> 1);
  }
  const float* xRow[2]; int aKc[2];
#pragma unroll
  for (int c2 = 0; c2 < 2; ++c2) {
    int P = c2 * 8192 + t * 16;
    int U = swz(P);
    xRow[c2] = x + (rbase + (U >> 7)) * (size_t)784;
    aKc[c2] = (U & 127) >> 1;
  }

  f32x4 acc[4][8];
#pragma unroll
  for (int m = 0; m < 4; ++m)
#pragma unroll
    for (int n = 0; n < 8; ++n) acc[m][n] = (f32x4){0.f, 0.f, 0.f, 0.f};

  bhalf8 afA[4], bf[4];
  f32x4 xrE[2][2], xrO[2][2];

  auto loadX = [&](int tt2, f32x4 (&xr)[2][2]) {
#pragma unroll
    for (int c2 = 0; c2 < 2; ++c2) {
      int k = tt2 * 64 + aKc[c2];
      const float* p = xRow[c2] + ((k < 784) ? k : 0);
      xr[c2][0] = *(const f32x4*)p; xr[c2][1] = *(const f32x4*)(p + 4);
    }
  };
  auto cvtW = [&](int aB, f32x4 (&xr)[2][2]) {
#pragma unroll
    for (int c2 = 0; c2 < 2; ++c2) {
      u16x8 v;
#pragma unroll
      for (int j = 0; j < 4; ++j) { v[j] = f2bf(xr[c2][0][j]); v[4 + j] = f2bf(xr[c2][1][j]); }
      *(u16x8*)(lds + aB + c2 * 8192 + t * 16) = v;
    }
  };
  auto gllLo = [&](int H) {
    char* bb = lds + 32768 + (H % 3) * 32768;
    GLL16(bSrcP[0] + H * 32, bb + (w * 4 + 0) * 1024);
    GLL16(bSrcP[1] + H * 32, bb + (w * 4 + 1) * 1024);
  };
  auto gllHi = [&](int H) {
    char* bb = lds + 32768 + (H % 3) * 32768;
    GLL16(bSrcP[2] + H * 32, bb + (w * 4 + 2) * 1024);
    GLL16(bSrcP[3] + H * 32, bb + (w * 4 + 3) * 1024);
  };
  auto rdA = [&](int aB, int ks) {
#pragma unroll
    for (int m = 0; m < 4; ++m)
      afA[m] = *(const bhalf8*)(lds + aB + (aO[m] ^ (ks << 6)));
  };
  auto rdBq = [&](int H, int hi) {
    const char* bb = lds + 32768 + (H % 3) * 32768 + hi * 4096;
#pragma unroll
    for (int j = 0; j < 4; ++j) bf[j] = *(const bhalf8*)(bb + bO[j]);
  };
  auto mfmaLoQ = [&]() {
    __builtin_amdgcn_s_setprio(1);
#pragma unroll
    for (int m = 0; m < 4; ++m)
#pragma unroll
      for (int n = 0; n < 4; ++n)
        acc[m][n] = __builtin_amdgcn_mfma_f32_16x16x32_bf16(afA[m], bf[n], acc[m][n], 0, 0, 0);
    __builtin_amdgcn_s_setprio(0);
  };
  auto mfmaHiQ = [&]() {
    __builtin_amdgcn_s_setprio(1);
#pragma unroll
    for (int m = 0; m < 4; ++m)
#pragma unroll
      for (int n = 0; n < 4; ++n)
        acc[m][4 + n] = __builtin_amdgcn_mfma_f32_16x16x32_bf16(afA[m], bf[n], acc[m][4 + n], 0, 0, 0);
    __builtin_amdgcn_s_setprio(0);
  };

  auto tile = [&](int tt, f32x4 (&xrLd)[2][2], f32x4 (&xrCv)[2][2],
                  bool doStage, bool doX, int vmPh4, bool vm0Ph2) {
    const int aB = (tt & 1) * 16384;
    const int H0 = 2 * tt, H1 = 2 * tt + 1;
    rdA(aB, 0); rdBq(H0, 0);
    if (doStage) gllLo(H0 + 2);
    __builtin_amdgcn_s_barrier();
    asm volatile("s_waitcnt lgkmcnt(0)" ::: "memory"); SB();
    mfmaLoQ();
    __builtin_amdgcn_s_barrier();
    rdBq(H0, 1);
    if (doStage) gllHi(H0 + 2);
    __builtin_amdgcn_s_barrier();
    asm volatile("s_waitcnt lgkmcnt(0)" ::: "memory"); SB();
    mfmaHiQ();
    if (vm0Ph2) { asm volatile("s_waitcnt vmcnt(0)" ::: "memory"); }
    else        { asm volatile("s_waitcnt vmcnt(4)" ::: "memory"); }
    __builtin_amdgcn_s_barrier();
    rdA(aB, 1); rdBq(H1, 0);
    if (doStage) gllLo(H1 + 2);
    if (doX) loadX(tt + 2, xrLd);
    __builtin_amdgcn_s_barrier();
    asm volatile("s_waitcnt lgkmcnt(0)" ::: "memory"); SB();
    mfmaLoQ();
    __builtin_amdgcn_s_barrier();
    rdBq(H1, 1);
    if (tt < 12) cvtW(aB ^ 16384, xrCv);
    if (doStage) gllHi(H1 + 2);
    __builtin_amdgcn_s_barrier();
    asm volatile("s_waitcnt lgkmcnt(0)" ::: "memory"); SB();
    mfmaHiQ();
    if (vmPh4 == 8)      { asm volatile("s_waitcnt vmcnt(8)" ::: "memory"); }
    else if (vmPh4 == 4) { asm volatile("s_waitcnt vmcnt(4)" ::: "memory"); }
    __builtin_amdgcn_s_barrier();
  };

  gllLo(0); gllHi(0);
  gllLo(1); gllHi(1);
  loadX(0, xrE);
  loadX(1, xrO);
  cvtW(0, xrE);
  asm volatile("s_waitcnt lgkmcnt(0)" ::: "memory");
  __builtin_amdgcn_s_barrier();

  for (int i = 0; i < 5; ++i) {
    tile(2 * i,     xrE, xrO, true, true, 8, false);
    tile(2 * i + 1, xrO, xrE, true, true, 8, false);
  }
  tile(10, xrE, xrO, true,  true,  8, false);
  tile(11, xrO, xrE, true,  false, 4, false);
  tile(12, xrE, xrO, false, false, -1, true);
  // all staging drained; acc holds the 128x512 m1 tile (pre-relu)

  // ====== layer-2 W1 staging sources (pre-swizzled, [256][32] 64B-row tiles) ======
  const u16* w1Src[2];
#pragma unroll
  for (int i = 0; i < 2; ++i) {
    int P = (w * 2 + i) * 1024 + lane * 16;
    int U = swz(P);
    w1Src[i] = W1b + (size_t)(U >> 6) * 512 + ((U & 63) >> 1);
  }
  // issue W1 tile-0 glls now: they fly under the m1 scatter
#pragma unroll
  for (int i = 0; i < 2; ++i) GLL16(w1Src[i], lds + 131072 + (w * 2 + i) * 1024);

  // ====== scatter relu(m1) -> LDS [128][512] bf16 (1024B rows, swzM); acc DIES ======
#pragma unroll
  for (int m = 0; m < 4; ++m)
#pragma unroll
    for (int n = 0; n < 8; ++n)
#pragma unroll
      for (int q = 0; q < 4; ++q) {
        int row = wr * 64 + m * 16 + fg * 4 + q;
        int col = wc * 128 + n * 16 + fr;
        float vv = acc[m][n][q];
        vv = vv > 0.f ? vv : 0.f;
        *(u16*)(lds + swzM(row * 1024 + col * 2)) = f2bf(vv);
      }
  __syncthreads();

  // ====== layer 2: m2[128][256] = relu(m1 @ W1^T), K=512, BK=32, 16 dbuf steps ======
  int a2O[4], b2O[4];
#pragma unroll
  for (int m = 0; m < 4; ++m) a2O[m] = (wr * 64 + m * 16 + fr) * 1024 + fg * 16;
#pragma unroll
  for (int n = 0; n < 4; ++n) b2O[n] = (wc * 64 + n * 16 + fr) * 64 + fg * 16;

  f32x4 acc2[4][4];
#pragma unroll
  for (int m = 0; m < 4; ++m)
#pragma unroll
    for (int n = 0; n < 4; ++n) acc2[m][n] = (f32x4){0.f, 0.f, 0.f, 0.f};

  for (int kt = 0; kt < 16; ++kt) {
    const char* wbuf = lds + 131072 + (kt & 1) * 16384;
    asm volatile("s_waitcnt vmcnt(0)" ::: "memory");
    __syncthreads();
    if (kt < 15) {
#pragma unroll
      for (int i = 0; i < 2; ++i)
        GLL16(w1Src[i] + (kt + 1) * 32,
              lds + 131072 + ((kt + 1) & 1) * 16384 + (w * 2 + i) * 1024);
    }
    bhalf8 a2[4], b2[4];
#pragma unroll
    for (int m = 0; m < 4; ++m)
      a2[m] = *(const bhalf8*)(lds + swzM(a2O[m] + kt * 64));
#pragma unroll
    for (int n = 0; n < 4; ++n)
      b2[n] = *(const bhalf8*)(wbuf + swz(b2O[n]));
    __builtin_amdgcn_s_setprio(1);
#pragma unroll
    for (int m = 0; m < 4; ++m)
#pragma unroll
      for (int n = 0; n < 4; ++n)
        acc2[m][n] = __builtin_amdgcn_mfma_f32_16x16x32_bf16(a2[m], b2[n], acc2[m][n], 0, 0, 0);
    __builtin_amdgcn_s_setprio(0);
  }
  __syncthreads();   // all m1 / W1-buf reads done; m1 region reusable

  // ====== m2 -> LDS [128][264] @0; W2 [16][264] @67584; layer 3 -> out ======
  u16* m2s = (u16*)lds;
  u16* W2s = (u16*)(lds + 67584);
  {
    int r = t >> 5, kc = (t & 31) * 8;
    *(int4*)&W2s[r * 264 + kc] = *(const int4*)(W2b + r * 256 + kc);
  }
#pragma unroll
  for (int m = 0; m < 4; ++m)
#pragma unroll
    for (int n = 0; n < 4; ++n)
#pragma unroll
      for (int q = 0; q < 4; ++q) {
        int row = wr * 64 + m * 16 + fg * 4 + q;
        int col = wc * 64 + n * 16 + fr;
        float vv = acc2[m][n][q];
        vv = vv > 0.f ? vv : 0.f;
        m2s[row * 264 + col] = f2bf(vv);
      }
  __syncthreads();

  // layer 3: 8 waves x 16 rows, K=256
  {
    f32x4 acc3 = (f32x4){0.f, 0.f, 0.f, 0.f};
    const int arow = w * 16 + fr;
#pragma unroll
    for (int ks = 0; ks < 8; ++ks) {
      bhalf8 a = *(const bhalf8*)&m2s[arow * 264 + ks * 32 + fg * 8];
      bhalf8 b = *(const bhalf8*)&W2s[fr * 264 + ks * 32 + fg * 8];
      acc3 = __builtin_amdgcn_mfma_f32_16x16x32_bf16(a, b, acc3, 0, 0, 0);
    }
    if (fr < 10) {
#pragma unroll
      for (int q = 0; q < 4; ++q) {
        size_t row = rbase + w * 16 + fg * 4 + q;
        float vv = acc3[q];
        out[row * 10 + fr] = vv > 0.f ? vv : 0.f;
      }
    }
  }
}

extern "C" void kernel_launch(void* const* d_in, const int* in_sizes, int n_in,
                              void* d_out, int out_size, void* d_ws, size_t ws_size,
                              hipStream_t stream) {
  const float* x  = (const float*)d_in[0];
  const float* W0 = (const float*)d_in[1];
  const float* W1 = (const float*)d_in[2];
  const float* W2 = (const float*)d_in[3];
  float* out = (float*)d_out;

  char* ws = (char*)d_ws;
  u16* W0b = (u16*)(ws);                    // 512x832 = 851968 B
  u16* W1b = (u16*)(ws + 851968);           // 256x512 = 262144 B
  u16* W2b = (u16*)(ws + 1114112);          // 16x256  = 8192 B

  hipFuncSetAttribute((const void*)fused3,
                      hipFuncAttributeMaxDynamicSharedMemorySize, 163840);

  cvt_weights<<<dim3((W0E + W1E + W2E + 255) / 256), dim3(256), 0, stream>>>(
      W0, W1, W2, W0b, W1b, W2b);

  // all three layers fused; m1/m2 never touch HBM; no register state crosses layers
  fused3<<<dim3(256), dim3(512), 163840, stream>>>(x, W0b, W1b, W2b, out);
}